// Round 7
// baseline (76.338 us; speedup 1.0000x reference)
//
#include <hip/hip_runtime.h>
#include <math.h>

namespace {
constexpr int KB    = 16;        // spline bins
constexpr int OUTP  = 3*KB + 1;  // 49
constexpr int CDIM  = 64;
constexpr int HDIM  = 256;
constexpr int NCOL  = 1024;
constexpr int NROW  = 4096;
constexpr float BOUNDF = 5.0f;
constexpr float MBW_ = 0.001f;
constexpr float MBH_ = 0.001f;
constexpr float MD_  = 0.001f;
constexpr int PSTR = 51;  // 17 cumw | 17 cumh | 17 deriv
constexpr int WPB  = 8;   // waves per block = rows per block
constexpr int NT   = WPB * 64;   // 512 threads
}

// ---------------------------------------------------------------------------
// One ROW per WAVE. All LDS producer->consumer is within a single wave
// (lockstep wave64 + lgkmcnt ordering) -> no cross-wave reductions, no
// correctness barriers. The 3 __syncthreads are phase-locks only: they keep
// the block's 8 waves streaming the same W region so L1/L2 serve the reuse.
// Lane owns 4 consecutive output cols (coalesced float4 W loads); broadcast
// activation comes as one ds_read_b128 per 4-k chunk; W tile and h chunk are
// register double-buffered.
// ---------------------------------------------------------------------------
__device__ __forceinline__ void layer_fc(const float* __restrict__ in_s,  // LDS row base, KDIM floats
                                         const float* __restrict__ W,    // [KDIM][HDIM]
                                         const float* __restrict__ b,    // [HDIM]
                                         float* __restrict__ out_s,      // LDS row base, HDIM floats
                                         int lane, int KDIM)
{
    const int c4 = 4*lane;
    float4 acc = make_float4(0.f, 0.f, 0.f, 0.f);

    float4 hv = *(const float4*)(in_s);
    float4 w0 = *(const float4*)(W + (size_t)0*HDIM + c4);
    float4 w1 = *(const float4*)(W + (size_t)1*HDIM + c4);
    float4 w2 = *(const float4*)(W + (size_t)2*HDIM + c4);
    float4 w3 = *(const float4*)(W + (size_t)3*HDIM + c4);

    const int NC = KDIM/4;
    #pragma unroll 2
    for (int kc = 0; kc < NC; ++kc) {
        const float4 hc = hv;
        const float4 v0 = w0, v1 = w1, v2 = w2, v3 = w3;
        if (kc + 1 < NC) {
            const int k0 = 4*(kc+1);
            hv = *(const float4*)(in_s + k0);
            w0 = *(const float4*)(W + (size_t)(k0+0)*HDIM + c4);
            w1 = *(const float4*)(W + (size_t)(k0+1)*HDIM + c4);
            w2 = *(const float4*)(W + (size_t)(k0+2)*HDIM + c4);
            w3 = *(const float4*)(W + (size_t)(k0+3)*HDIM + c4);
        }
        acc.x = fmaf(hc.x, v0.x, acc.x); acc.y = fmaf(hc.x, v0.y, acc.y);
        acc.z = fmaf(hc.x, v0.z, acc.z); acc.w = fmaf(hc.x, v0.w, acc.w);
        acc.x = fmaf(hc.y, v1.x, acc.x); acc.y = fmaf(hc.y, v1.y, acc.y);
        acc.z = fmaf(hc.y, v1.z, acc.z); acc.w = fmaf(hc.y, v1.w, acc.w);
        acc.x = fmaf(hc.z, v2.x, acc.x); acc.y = fmaf(hc.z, v2.y, acc.y);
        acc.z = fmaf(hc.z, v2.z, acc.z); acc.w = fmaf(hc.z, v2.w, acc.w);
        acc.x = fmaf(hc.w, v3.x, acc.x); acc.y = fmaf(hc.w, v3.y, acc.y);
        acc.z = fmaf(hc.w, v3.z, acc.z); acc.w = fmaf(hc.w, v3.w, acc.w);
    }
    const float4 bb = *(const float4*)(b + c4);
    *(float4*)(out_s + c4) = make_float4(
        fmaxf(acc.x + bb.x, 0.f), fmaxf(acc.y + bb.y, 0.f),
        fmaxf(acc.z + bb.z, 0.f), fmaxf(acc.w + bb.w, 0.f));
}

__global__ __launch_bounds__(NT) void mlp_params_kernel(
    const float* __restrict__ cond,
    const float* __restrict__ W1, const float* __restrict__ b1,
    const float* __restrict__ W2, const float* __restrict__ b2,
    const float* __restrict__ W3, const float* __restrict__ b3,
    float* __restrict__ params)
{
    __shared__ float cond_s[WPB][CDIM];   //  2   KB
    __shared__ float h1_s[WPB][HDIM];     //  8   KB
    __shared__ float h2_s[WPB][HDIM];     //  8   KB
    __shared__ float p_s[WPB][OUTP];      //  1.6 KB
    __shared__ float prm_s[WPB][PSTR];    //  1.6 KB

    const int tid  = threadIdx.x;
    const int lane = tid & 63;
    const int wid  = tid >> 6;                 // 0..7
    const int row  = blockIdx.x * WPB + wid;   // this wave's row

    // stage this wave's cond row (256B coalesced; consumed by same wave)
    cond_s[wid][lane] = cond[(size_t)row*CDIM + lane];
    __syncthreads();   // phase-lock

    // layer 1: h1 = relu(cond @ W1 + b1)
    layer_fc(&cond_s[wid][0], W1, b1, &h1_s[wid][0], lane, CDIM);
    __syncthreads();   // phase-lock (keeps 8 waves on same W2 region next)

    // layer 2: h2 = relu(h1 @ W2 + b2)
    layer_fc(&h1_s[wid][0], W2, b2, &h2_s[wid][0], lane, HDIM);
    __syncthreads();   // phase-lock

    // layer 3: p = h2 @ W3 + b3 ; lane = output unit (49 active)
    {
        const int  o   = lane;
        const bool act = (o < OUTP);
        float acc = 0.f;
        float4 hv = *(const float4*)&h2_s[wid][0];
        float wk0 = act ? W3[(size_t)0*OUTP + o] : 0.f;
        float wk1 = act ? W3[(size_t)1*OUTP + o] : 0.f;
        float wk2 = act ? W3[(size_t)2*OUTP + o] : 0.f;
        float wk3 = act ? W3[(size_t)3*OUTP + o] : 0.f;
        #pragma unroll 2
        for (int kc = 0; kc < HDIM/4; ++kc) {
            const float4 hc = hv;
            const float v0 = wk0, v1 = wk1, v2 = wk2, v3 = wk3;
            if (kc + 1 < HDIM/4) {
                const int k0 = 4*(kc+1);
                hv  = *(const float4*)&h2_s[wid][k0];
                wk0 = act ? W3[(size_t)(k0+0)*OUTP + o] : 0.f;
                wk1 = act ? W3[(size_t)(k0+1)*OUTP + o] : 0.f;
                wk2 = act ? W3[(size_t)(k0+2)*OUTP + o] : 0.f;
                wk3 = act ? W3[(size_t)(k0+3)*OUTP + o] : 0.f;
            }
            acc = fmaf(hc.x, v0, acc);
            acc = fmaf(hc.y, v1, acc);
            acc = fmaf(hc.z, v2, acc);
            acc = fmaf(hc.w, v3, acc);
        }
        if (act) p_s[wid][o] = acc + b3[o];
    }
    // same-wave LDS ordering (lgkmcnt) makes p_s visible to lanes 0..2 below

    // softmax+cumsum (lanes 0,1) and softplus (lane 2) for this wave's row
    if (lane < 2) {
        const int   off   = (lane == 0) ? 0 : KB;
        const int   cbase = (lane == 0) ? 0 : 17;
        const float mb    = (lane == 0) ? MBW_ : MBH_;
        float m = -1e30f;
        #pragma unroll
        for (int i = 0; i < KB; ++i) m = fmaxf(m, p_s[wid][off+i]);
        float e[KB];
        float s = 0.f;
        #pragma unroll
        for (int i = 0; i < KB; ++i) { e[i] = __expf(p_s[wid][off+i] - m); s += e[i]; }
        const float span = (2.f*BOUNDF - (float)KB*mb) / s;
        float c = -BOUNDF;
        prm_s[wid][cbase] = c;
        #pragma unroll
        for (int i = 0; i < KB; ++i) {
            c += mb + span*e[i];
            prm_s[wid][cbase + 1 + i] = c;
        }
    }
    if (lane == 2) {
        #pragma unroll
        for (int i = 0; i < KB+1; ++i) {
            const float x  = p_s[wid][2*KB + i];
            const float sp = (x > 20.f) ? x : __logf(1.f + __expf(x));
            prm_s[wid][34 + i] = MD_ + sp;
        }
    }
    // same-wave ordering again; dump packed params
    if (lane < PSTR)
        params[(size_t)row*PSTR + lane] = prm_s[wid][lane];
}

// ---------------------------------------------------------------------------
// Spline application (unchanged from R5): 4096 blocks (1 row each) ->
// 8 blocks/CU resident; packed 32B bin records (1 b128 + 1 b64 per element);
// single fast log for logdet.
// ---------------------------------------------------------------------------
__global__ __launch_bounds__(256) void spline_kernel(
    const float* __restrict__ y,
    const float* __restrict__ params,
    float* __restrict__ out,
    float* __restrict__ logdet)
{
    __shared__ float prm[PSTR];
    __shared__ float rec[KB][8];
    __shared__ float scan_s[KB];

    const int b   = blockIdx.x;
    const int tid = threadIdx.x;
    if (tid < PSTR) prm[tid] = params[(size_t)b*PSTR + tid];
    __syncthreads();
    if (tid < KB) {
        const int k = tid;
        rec[k][0] = prm[k];        rec[k][1] = prm[k+1];
        rec[k][2] = prm[17+k];     rec[k][3] = prm[17+k+1];
        rec[k][4] = prm[34+k];     rec[k][5] = prm[34+k+1];
        rec[k][6] = 0.f;           rec[k][7] = 0.f;
        scan_s[k] = prm[k+1];      // thresholds cumw[1..16]
    }
    __syncthreads();

    float cw[KB];
    #pragma unroll
    for (int q = 0; q < 4; ++q) {
        const float4 t4 = *(const float4*)&scan_s[4*q];   // uniform broadcast
        cw[4*q+0] = t4.x; cw[4*q+1] = t4.y; cw[4*q+2] = t4.z; cw[4*q+3] = t4.w;
    }

    const size_t base = (size_t)b * NCOL + 4*tid;
    const float4 yv   = *(const float4*)(y + base);
    const float  yy[4] = {yv.x, yv.y, yv.z, yv.w};
    float ov[4], lv[4];

    #pragma unroll
    for (int i = 0; i < 4; ++i) {
        const float yi = yy[i];
        const bool outside = (yi < -BOUNDF) || (yi > BOUNDF);
        const float xc = fminf(fmaxf(yi, -BOUNDF), BOUNDF);
        int bin = 0;
        #pragma unroll
        for (int k = 0; k < KB; ++k) bin += (xc >= cw[k]) ? 1 : 0;
        bin = min(bin, KB-1);

        const float4 lo = *(const float4*)&rec[bin][0];   // ds_read_b128
        const float2 hi = *(const float2*)&rec[bin][4];   // ds_read_b64
        const float w  = lo.y - lo.x;
        const float hh = lo.w - lo.z;
        const float d0 = hi.x, d1 = hi.y;

        const float inv_w = __fdividef(1.f, w);
        const float delta = hh * inv_w;
        const float theta = (xc - lo.x) * inv_w;
        const float omt   = 1.f - theta;
        const float tt    = theta * theta;
        const float tomt  = theta * omt;
        const float num   = hh * (delta*tt + d0*tomt);
        const float den   = delta + (d0 + d1 - 2.f*delta)*tomt;
        const float o     = lo.z + __fdividef(num, den);
        const float der_num = fmaxf(delta*delta*(d1*tt + 2.f*delta*tomt + d0*omt*omt), 1e-12f);
        const float der_den = fmaxf(den*den, 1e-12f);
        const float ld      = __logf(__fdividef(der_num, der_den));

        ov[i] = outside ? yi : o;
        lv[i] = outside ? 0.f : ld;
    }

    *(float4*)(out + base)    = make_float4(ov[0], ov[1], ov[2], ov[3]);
    *(float4*)(logdet + base) = make_float4(lv[0], lv[1], lv[2], lv[3]);
}

extern "C" void kernel_launch(void* const* d_in, const int* in_sizes, int n_in,
                              void* d_out, int out_size, void* d_ws, size_t ws_size,
                              hipStream_t stream) {
    const float* cond = (const float*)d_in[0];
    const float* y    = (const float*)d_in[1];
    const float* W1   = (const float*)d_in[2];
    const float* b1   = (const float*)d_in[3];
    const float* W2   = (const float*)d_in[4];
    const float* b2   = (const float*)d_in[5];
    const float* W3   = (const float*)d_in[6];
    const float* b3   = (const float*)d_in[7];

    float* out    = (float*)d_out;
    float* logdet = out + (size_t)NROW * NCOL;
    float* params = (float*)d_ws;   // 4096 * 51 floats = 0.84 MB

    mlp_params_kernel<<<NROW/WPB, NT, 0, stream>>>(cond, W1, b1, W2, b2, W3, b3, params);
    spline_kernel<<<NROW, 256, 0, stream>>>(y, params, out, logdet);
}

// Round 8
// 40.321 us; speedup vs baseline: 1.8933x; 1.8933x over previous
//
#include <hip/hip_runtime.h>
#include <math.h>

namespace {
constexpr int KB    = 16;        // spline bins
constexpr int OUTP  = 3*KB + 1;  // 49
constexpr int CDIM  = 64;
constexpr int HDIM  = 256;
constexpr int NCOL  = 1024;
constexpr int NROW  = 4096;
constexpr float BOUNDF = 5.0f;
constexpr float MBW_ = 0.001f;
constexpr float MBH_ = 0.001f;
constexpr float MD_  = 0.001f;
constexpr int PSTR = 51;  // 17 cumw | 17 cumh | 17 deriv
constexpr int NR   = 4;   // rows per block (MLP)  [R5 had 8; 4 -> 2x blocks/CU]
}

// ---------------------------------------------------------------------------
// Kernel A: MLP -> spline params. 1024 blocks x 4 waves (256 thr), 4-way
// split-K (wave owns K/4; lane owns 4 consecutive cols -> coalesced float4 W
// loads, W read exactly once per block). ~23 KB LDS -> 4 blocks/CU = 16
// waves/CU: double R5's latency hiding; W L2 traffic 2x (overlapped).
// ---------------------------------------------------------------------------
__global__ __launch_bounds__(256) void mlp_params_kernel(
    const float* __restrict__ cond,
    const float* __restrict__ W1, const float* __restrict__ b1,
    const float* __restrict__ W2, const float* __restrict__ b2,
    const float* __restrict__ W3, const float* __restrict__ b3,
    float* __restrict__ params)
{
    __shared__ float cond_s[NR][CDIM];       //  1   KB
    __shared__ float ps[4][NR][HDIM];        // 16   KB
    __shared__ float h_s[NR][HDIM];          //  4   KB (h1 then h2)
    __shared__ float p_s[NR][OUTP];          //  0.8 KB
    __shared__ float prm_s[NR][PSTR];        //  0.8 KB

    const int tid  = threadIdx.x;
    const int lane = tid & 63;
    const int wid  = tid >> 6;
    const int row0 = blockIdx.x * NR;

    if (tid < NR*CDIM/4)
        *((float4*)&cond_s[0][0] + tid) = *((const float4*)(cond + (size_t)row0*CDIM) + tid);
    __syncthreads();

    // ---- layer 1: wave owns k in [16w, 16w+16)
    {
        float acc[NR][4];
        #pragma unroll
        for (int r = 0; r < NR; ++r)
            #pragma unroll
            for (int c = 0; c < 4; ++c) acc[r][c] = 0.f;

        #pragma unroll
        for (int kg = 0; kg < 4; ++kg) {
            const int k0 = 16*wid + 4*kg;
            float4 wv[4];
            #pragma unroll
            for (int kk = 0; kk < 4; ++kk)
                wv[kk] = *(const float4*)(W1 + (size_t)(k0+kk)*HDIM + 4*lane);
            #pragma unroll
            for (int r = 0; r < NR; ++r) {
                const float4 cv4 = *(const float4*)&cond_s[r][k0];
                const float cv[4] = {cv4.x, cv4.y, cv4.z, cv4.w};
                const float wf[4][4] = {{wv[0].x,wv[0].y,wv[0].z,wv[0].w},
                                        {wv[1].x,wv[1].y,wv[1].z,wv[1].w},
                                        {wv[2].x,wv[2].y,wv[2].z,wv[2].w},
                                        {wv[3].x,wv[3].y,wv[3].z,wv[3].w}};
                #pragma unroll
                for (int kk = 0; kk < 4; ++kk)
                    #pragma unroll
                    for (int c = 0; c < 4; ++c)
                        acc[r][c] = fmaf(cv[kk], wf[kk][c], acc[r][c]);
            }
        }
        #pragma unroll
        for (int r = 0; r < NR; ++r)
            *(float4*)&ps[wid][r][4*lane] = make_float4(acc[r][0], acc[r][1], acc[r][2], acc[r][3]);
    }
    __syncthreads();
    {
        const float bb = b1[tid];
        #pragma unroll
        for (int r = 0; r < NR; ++r)
            h_s[r][tid] = fmaxf(ps[0][r][tid] + ps[1][r][tid] + ps[2][r][tid] + ps[3][r][tid] + bb, 0.f);
    }
    __syncthreads();

    // ---- layer 2: wave owns k in [64w, 64w+64); register-prefetched W tiles
    {
        float acc[NR][4];
        #pragma unroll
        for (int r = 0; r < NR; ++r)
            #pragma unroll
            for (int c = 0; c < 4; ++c) acc[r][c] = 0.f;

        float4 wn[4];
        #pragma unroll
        for (int kk = 0; kk < 4; ++kk)
            wn[kk] = *(const float4*)(W2 + (size_t)(64*wid+kk)*HDIM + 4*lane);

        #pragma unroll 2
        for (int kg = 0; kg < 16; ++kg) {
            const int k0 = 64*wid + 4*kg;
            float4 wv[4];
            #pragma unroll
            for (int kk = 0; kk < 4; ++kk) wv[kk] = wn[kk];
            if (kg < 15) {
                #pragma unroll
                for (int kk = 0; kk < 4; ++kk)
                    wn[kk] = *(const float4*)(W2 + (size_t)(k0+4+kk)*HDIM + 4*lane);
            }
            #pragma unroll
            for (int r = 0; r < NR; ++r) {
                const float4 hv4 = *(const float4*)&h_s[r][k0];
                const float hv[4] = {hv4.x, hv4.y, hv4.z, hv4.w};
                const float wf[4][4] = {{wv[0].x,wv[0].y,wv[0].z,wv[0].w},
                                        {wv[1].x,wv[1].y,wv[1].z,wv[1].w},
                                        {wv[2].x,wv[2].y,wv[2].z,wv[2].w},
                                        {wv[3].x,wv[3].y,wv[3].z,wv[3].w}};
                #pragma unroll
                for (int kk = 0; kk < 4; ++kk)
                    #pragma unroll
                    for (int c = 0; c < 4; ++c)
                        acc[r][c] = fmaf(hv[kk], wf[kk][c], acc[r][c]);
            }
        }
        #pragma unroll
        for (int r = 0; r < NR; ++r)
            *(float4*)&ps[wid][r][4*lane] = make_float4(acc[r][0], acc[r][1], acc[r][2], acc[r][3]);
    }
    __syncthreads();
    {
        const float bb = b2[tid];
        float hn[NR];
        #pragma unroll
        for (int r = 0; r < NR; ++r)
            hn[r] = fmaxf(ps[0][r][tid] + ps[1][r][tid] + ps[2][r][tid] + ps[3][r][tid] + bb, 0.f);
        __syncthreads();          // all h1 reads done before overwrite
        #pragma unroll
        for (int r = 0; r < NR; ++r) h_s[r][tid] = hn[r];
    }
    __syncthreads();

    // ---- layer 3: lane = output unit, wave owns k-slice
    {
        const int  o   = lane;
        const bool act = (o < OUTP);
        float acc[NR];
        #pragma unroll
        for (int r = 0; r < NR; ++r) acc[r] = 0.f;

        #pragma unroll 4
        for (int kg = 0; kg < 16; ++kg) {
            const int k0 = 64*wid + 4*kg;
            float wv[4];
            #pragma unroll
            for (int kk = 0; kk < 4; ++kk)
                wv[kk] = act ? W3[(size_t)(k0+kk)*OUTP + o] : 0.f;
            #pragma unroll
            for (int r = 0; r < NR; ++r) {
                const float4 hv = *(const float4*)&h_s[r][k0];
                acc[r] = fmaf(hv.x, wv[0], acc[r]);
                acc[r] = fmaf(hv.y, wv[1], acc[r]);
                acc[r] = fmaf(hv.z, wv[2], acc[r]);
                acc[r] = fmaf(hv.w, wv[3], acc[r]);
            }
        }
        if (act) {
            #pragma unroll
            for (int r = 0; r < NR; ++r) ps[wid][r][o] = acc[r];
        }
    }
    __syncthreads();
    for (int t = tid; t < NR*OUTP; t += 256) {
        const int r = t / OUTP;
        const int o = t - r*OUTP;
        p_s[r][o] = ps[0][r][o] + ps[1][r][o] + ps[2][r][o] + ps[3][r][o] + b3[o];
    }
    __syncthreads();

    // ---- softmax+cumsum (widths, heights) and softplus (derivs)
    if (tid < NR*3) {
        const int r   = tid / 3;
        const int seg = tid - 3*r;
        if (seg < 2) {
            const int   off   = (seg == 0) ? 0 : KB;
            const int   cbase = (seg == 0) ? 0 : 17;
            const float mb    = (seg == 0) ? MBW_ : MBH_;
            float m = -1e30f;
            #pragma unroll
            for (int i = 0; i < KB; ++i) m = fmaxf(m, p_s[r][off+i]);
            float e[KB];
            float s = 0.f;
            #pragma unroll
            for (int i = 0; i < KB; ++i) { e[i] = __expf(p_s[r][off+i] - m); s += e[i]; }
            const float span = (2.f*BOUNDF - (float)KB*mb) / s;
            float c = -BOUNDF;
            prm_s[r][cbase] = c;
            #pragma unroll
            for (int i = 0; i < KB; ++i) {
                c += mb + span*e[i];
                prm_s[r][cbase + 1 + i] = c;
            }
        } else {
            #pragma unroll
            for (int i = 0; i < KB+1; ++i) {
                const float x  = p_s[r][2*KB + i];
                const float sp = (x > 20.f) ? x : __logf(1.f + __expf(x));
                prm_s[r][34 + i] = MD_ + sp;
            }
        }
    }
    __syncthreads();

    for (int i = tid; i < NR*PSTR; i += 256)
        params[(size_t)row0*PSTR + i] = (&prm_s[0][0])[i];
}

// ---------------------------------------------------------------------------
// Kernel B: spline application (unchanged from R5, the 38 us best). 4096
// blocks (1 row each, ~1.3 KB LDS). Packed 32B bin records: 1 ds_read_b128 +
// 1 ds_read_b64 per element; single fast log for logdet.
// ---------------------------------------------------------------------------
__global__ __launch_bounds__(256) void spline_kernel(
    const float* __restrict__ y,
    const float* __restrict__ params,
    float* __restrict__ out,
    float* __restrict__ logdet)
{
    __shared__ float prm[PSTR];
    __shared__ float rec[KB][8];
    __shared__ float scan_s[KB];

    const int b   = blockIdx.x;
    const int tid = threadIdx.x;
    if (tid < PSTR) prm[tid] = params[(size_t)b*PSTR + tid];
    __syncthreads();
    if (tid < KB) {
        const int k = tid;
        rec[k][0] = prm[k];        rec[k][1] = prm[k+1];
        rec[k][2] = prm[17+k];     rec[k][3] = prm[17+k+1];
        rec[k][4] = prm[34+k];     rec[k][5] = prm[34+k+1];
        rec[k][6] = 0.f;           rec[k][7] = 0.f;
        scan_s[k] = prm[k+1];      // thresholds cumw[1..16]
    }
    __syncthreads();

    float cw[KB];
    #pragma unroll
    for (int q = 0; q < 4; ++q) {
        const float4 t4 = *(const float4*)&scan_s[4*q];   // uniform broadcast
        cw[4*q+0] = t4.x; cw[4*q+1] = t4.y; cw[4*q+2] = t4.z; cw[4*q+3] = t4.w;
    }

    const size_t base = (size_t)b * NCOL + 4*tid;
    const float4 yv   = *(const float4*)(y + base);
    const float  yy[4] = {yv.x, yv.y, yv.z, yv.w};
    float ov[4], lv[4];

    #pragma unroll
    for (int i = 0; i < 4; ++i) {
        const float yi = yy[i];
        const bool outside = (yi < -BOUNDF) || (yi > BOUNDF);
        const float xc = fminf(fmaxf(yi, -BOUNDF), BOUNDF);
        int bin = 0;
        #pragma unroll
        for (int k = 0; k < KB; ++k) bin += (xc >= cw[k]) ? 1 : 0;
        bin = min(bin, KB-1);

        const float4 lo = *(const float4*)&rec[bin][0];   // ds_read_b128
        const float2 hi = *(const float2*)&rec[bin][4];   // ds_read_b64
        const float w  = lo.y - lo.x;
        const float hh = lo.w - lo.z;
        const float d0 = hi.x, d1 = hi.y;

        const float inv_w = __fdividef(1.f, w);
        const float delta = hh * inv_w;
        const float theta = (xc - lo.x) * inv_w;
        const float omt   = 1.f - theta;
        const float tt    = theta * theta;
        const float tomt  = theta * omt;
        const float num   = hh * (delta*tt + d0*tomt);
        const float den   = delta + (d0 + d1 - 2.f*delta)*tomt;
        const float o     = lo.z + __fdividef(num, den);
        const float der_num = fmaxf(delta*delta*(d1*tt + 2.f*delta*tomt + d0*omt*omt), 1e-12f);
        const float der_den = fmaxf(den*den, 1e-12f);
        const float ld      = __logf(__fdividef(der_num, der_den));

        ov[i] = outside ? yi : o;
        lv[i] = outside ? 0.f : ld;
    }

    *(float4*)(out + base)    = make_float4(ov[0], ov[1], ov[2], ov[3]);
    *(float4*)(logdet + base) = make_float4(lv[0], lv[1], lv[2], lv[3]);
}

extern "C" void kernel_launch(void* const* d_in, const int* in_sizes, int n_in,
                              void* d_out, int out_size, void* d_ws, size_t ws_size,
                              hipStream_t stream) {
    const float* cond = (const float*)d_in[0];
    const float* y    = (const float*)d_in[1];
    const float* W1   = (const float*)d_in[2];
    const float* b1   = (const float*)d_in[3];
    const float* W2   = (const float*)d_in[4];
    const float* b2   = (const float*)d_in[5];
    const float* W3   = (const float*)d_in[6];
    const float* b3   = (const float*)d_in[7];

    float* out    = (float*)d_out;
    float* logdet = out + (size_t)NROW * NCOL;
    float* params = (float*)d_ws;   // 4096 * 51 floats = 0.84 MB

    mlp_params_kernel<<<NROW/NR, 256, 0, stream>>>(cond, W1, b1, W2, b2, W3, b3, params);
    spline_kernel<<<NROW, 256, 0, stream>>>(y, params, out, logdet);
}

// Round 9
// 39.027 us; speedup vs baseline: 1.9560x; 1.0332x over previous
//
#include <hip/hip_runtime.h>
#include <math.h>

namespace {
constexpr int KB    = 16;        // spline bins
constexpr int OUTP  = 3*KB + 1;  // 49
constexpr int CDIM  = 64;
constexpr int HDIM  = 256;
constexpr int NCOL  = 1024;
constexpr int NROW  = 4096;
constexpr float BOUNDF = 5.0f;
constexpr float MBW_ = 0.001f;
constexpr float MBH_ = 0.001f;
constexpr float MD_  = 0.001f;
constexpr int PSTR = 51;  // 17 cumw | 17 cumh | 17 deriv
constexpr int NR   = 8;   // rows per block (MLP)
constexpr int NT   = 512; // threads per MLP block (8 waves)
constexpr int RH   = NR/2; // rows per wave (row-half)
}

// ---------------------------------------------------------------------------
// Kernel A: MLP -> spline params. 512 blocks x 8 waves. Waves 2s,2s+1 own
// k-slice s (4-way split-K, same as R5); wave 2s computes rows 0-3, wave
// 2s+1 rows 4-7 (row-half split). Per-block LDS instr count, LDS size
// (45 KB -> 2 blocks/CU), and W traffic (once/block) are IDENTICAL to the
// 38us R5 config; waves/SIMD doubles 2->4. Twin waves' duplicate W loads
// hit L1. No RMW phases (R6's failure mode).
// ---------------------------------------------------------------------------
__global__ __launch_bounds__(NT) void mlp_params_kernel(
    const float* __restrict__ cond,
    const float* __restrict__ W1, const float* __restrict__ b1,
    const float* __restrict__ W2, const float* __restrict__ b2,
    const float* __restrict__ W3, const float* __restrict__ b3,
    float* __restrict__ params)
{
    __shared__ float cond_s[NR][CDIM];       //  2   KB
    __shared__ float ps[4][NR][HDIM];        // 32   KB
    __shared__ float h_s[NR][HDIM];          //  8   KB (h1 then h2)
    __shared__ float p_s[NR][OUTP];          //  1.6 KB
    __shared__ float prm_s[NR][PSTR];        //  1.6 KB

    const int tid   = threadIdx.x;
    const int lane  = tid & 63;
    const int wid   = tid >> 6;        // 0..7
    const int slot  = wid >> 1;        // k-slice 0..3
    const int rbase = (wid & 1) * RH;  // row-half 0 or 4
    const int row0  = blockIdx.x * NR;

    if (tid < NR*CDIM/4)
        *((float4*)&cond_s[0][0] + tid) = *((const float4*)(cond + (size_t)row0*CDIM) + tid);
    __syncthreads();

    // ---- layer 1: wave-pair owns k in [16s, 16s+16); wave does its 4 rows
    {
        float acc[RH][4];
        #pragma unroll
        for (int r = 0; r < RH; ++r)
            #pragma unroll
            for (int c = 0; c < 4; ++c) acc[r][c] = 0.f;

        #pragma unroll
        for (int kg = 0; kg < 4; ++kg) {
            const int k0 = 16*slot + 4*kg;
            float4 wv[4];
            #pragma unroll
            for (int kk = 0; kk < 4; ++kk)
                wv[kk] = *(const float4*)(W1 + (size_t)(k0+kk)*HDIM + 4*lane);
            #pragma unroll
            for (int r = 0; r < RH; ++r) {
                const float4 cv4 = *(const float4*)&cond_s[rbase + r][k0];
                const float cv[4] = {cv4.x, cv4.y, cv4.z, cv4.w};
                const float wf[4][4] = {{wv[0].x,wv[0].y,wv[0].z,wv[0].w},
                                        {wv[1].x,wv[1].y,wv[1].z,wv[1].w},
                                        {wv[2].x,wv[2].y,wv[2].z,wv[2].w},
                                        {wv[3].x,wv[3].y,wv[3].z,wv[3].w}};
                #pragma unroll
                for (int kk = 0; kk < 4; ++kk)
                    #pragma unroll
                    for (int c = 0; c < 4; ++c)
                        acc[r][c] = fmaf(cv[kk], wf[kk][c], acc[r][c]);
            }
        }
        #pragma unroll
        for (int r = 0; r < RH; ++r)
            *(float4*)&ps[slot][rbase + r][4*lane] =
                make_float4(acc[r][0], acc[r][1], acc[r][2], acc[r][3]);
    }
    __syncthreads();
    // reduce partials -> h1 (512 thr cover 8x256 in 4 steps)
    for (int t = tid; t < NR*HDIM; t += NT) {
        const int r = t >> 8;
        const int c = t & 255;
        h_s[r][c] = fmaxf(ps[0][r][c] + ps[1][r][c] + ps[2][r][c] + ps[3][r][c] + b1[c], 0.f);
    }
    __syncthreads();

    // ---- layer 2: wave-pair owns k in [64s, 64s+64); register-prefetched W
    {
        float acc[RH][4];
        #pragma unroll
        for (int r = 0; r < RH; ++r)
            #pragma unroll
            for (int c = 0; c < 4; ++c) acc[r][c] = 0.f;

        float4 wn[4];
        #pragma unroll
        for (int kk = 0; kk < 4; ++kk)
            wn[kk] = *(const float4*)(W2 + (size_t)(64*slot+kk)*HDIM + 4*lane);

        #pragma unroll 2
        for (int kg = 0; kg < 16; ++kg) {
            const int k0 = 64*slot + 4*kg;
            float4 wv[4];
            #pragma unroll
            for (int kk = 0; kk < 4; ++kk) wv[kk] = wn[kk];
            if (kg < 15) {
                #pragma unroll
                for (int kk = 0; kk < 4; ++kk)
                    wn[kk] = *(const float4*)(W2 + (size_t)(k0+4+kk)*HDIM + 4*lane);
            }
            #pragma unroll
            for (int r = 0; r < RH; ++r) {
                const float4 hv4 = *(const float4*)&h_s[rbase + r][k0];
                const float hv[4] = {hv4.x, hv4.y, hv4.z, hv4.w};
                const float wf[4][4] = {{wv[0].x,wv[0].y,wv[0].z,wv[0].w},
                                        {wv[1].x,wv[1].y,wv[1].z,wv[1].w},
                                        {wv[2].x,wv[2].y,wv[2].z,wv[2].w},
                                        {wv[3].x,wv[3].y,wv[3].z,wv[3].w}};
                #pragma unroll
                for (int kk = 0; kk < 4; ++kk)
                    #pragma unroll
                    for (int c = 0; c < 4; ++c)
                        acc[r][c] = fmaf(hv[kk], wf[kk][c], acc[r][c]);
            }
        }
        #pragma unroll
        for (int r = 0; r < RH; ++r)
            *(float4*)&ps[slot][rbase + r][4*lane] =
                make_float4(acc[r][0], acc[r][1], acc[r][2], acc[r][3]);
    }
    __syncthreads();   // all layer-2 work (incl. h1 reads) complete
    // reduce partials -> h2 (overwrite h_s is safe: h1 reads all done)
    for (int t = tid; t < NR*HDIM; t += NT) {
        const int r = t >> 8;
        const int c = t & 255;
        h_s[r][c] = fmaxf(ps[0][r][c] + ps[1][r][c] + ps[2][r][c] + ps[3][r][c] + b2[c], 0.f);
    }
    __syncthreads();

    // ---- layer 3: lane = output unit; wave-pair owns k-slice, wave its rows
    {
        const int  o   = lane;
        const bool act = (o < OUTP);
        float acc[RH];
        #pragma unroll
        for (int r = 0; r < RH; ++r) acc[r] = 0.f;

        #pragma unroll 4
        for (int kg = 0; kg < 16; ++kg) {
            const int k0 = 64*slot + 4*kg;
            float wv[4];
            #pragma unroll
            for (int kk = 0; kk < 4; ++kk)
                wv[kk] = act ? W3[(size_t)(k0+kk)*OUTP + o] : 0.f;
            #pragma unroll
            for (int r = 0; r < RH; ++r) {
                const float4 hv = *(const float4*)&h_s[rbase + r][k0];
                acc[r] = fmaf(hv.x, wv[0], acc[r]);
                acc[r] = fmaf(hv.y, wv[1], acc[r]);
                acc[r] = fmaf(hv.z, wv[2], acc[r]);
                acc[r] = fmaf(hv.w, wv[3], acc[r]);
            }
        }
        if (act) {
            #pragma unroll
            for (int r = 0; r < RH; ++r) ps[slot][rbase + r][o] = acc[r];
        }
    }
    __syncthreads();
    for (int t = tid; t < NR*OUTP; t += NT) {
        const int r = t / OUTP;
        const int o = t - r*OUTP;
        p_s[r][o] = ps[0][r][o] + ps[1][r][o] + ps[2][r][o] + ps[3][r][o] + b3[o];
    }
    __syncthreads();

    // ---- softmax+cumsum (widths, heights) and softplus (derivs)
    if (tid < NR*3) {
        const int r   = tid / 3;
        const int seg = tid - 3*r;
        if (seg < 2) {
            const int   off   = (seg == 0) ? 0 : KB;
            const int   cbase = (seg == 0) ? 0 : 17;
            const float mb    = (seg == 0) ? MBW_ : MBH_;
            float m = -1e30f;
            #pragma unroll
            for (int i = 0; i < KB; ++i) m = fmaxf(m, p_s[r][off+i]);
            float e[KB];
            float s = 0.f;
            #pragma unroll
            for (int i = 0; i < KB; ++i) { e[i] = __expf(p_s[r][off+i] - m); s += e[i]; }
            const float span = (2.f*BOUNDF - (float)KB*mb) / s;
            float c = -BOUNDF;
            prm_s[r][cbase] = c;
            #pragma unroll
            for (int i = 0; i < KB; ++i) {
                c += mb + span*e[i];
                prm_s[r][cbase + 1 + i] = c;
            }
        } else {
            #pragma unroll
            for (int i = 0; i < KB+1; ++i) {
                const float x  = p_s[r][2*KB + i];
                const float sp = (x > 20.f) ? x : __logf(1.f + __expf(x));
                prm_s[r][34 + i] = MD_ + sp;
            }
        }
    }
    __syncthreads();

    for (int i = tid; i < NR*PSTR; i += NT)
        params[(size_t)row0*PSTR + i] = (&prm_s[0][0])[i];
}

// ---------------------------------------------------------------------------
// Kernel B: spline application (verbatim from R5 best). 4096 blocks (1 row
// each, ~1.3 KB LDS). Packed 32B bin records: 1 ds_read_b128 + 1 ds_read_b64
// per element; single fast log for logdet.
// ---------------------------------------------------------------------------
__global__ __launch_bounds__(256) void spline_kernel(
    const float* __restrict__ y,
    const float* __restrict__ params,
    float* __restrict__ out,
    float* __restrict__ logdet)
{
    __shared__ float prm[PSTR];
    __shared__ float rec[KB][8];
    __shared__ float scan_s[KB];

    const int b   = blockIdx.x;
    const int tid = threadIdx.x;
    if (tid < PSTR) prm[tid] = params[(size_t)b*PSTR + tid];
    __syncthreads();
    if (tid < KB) {
        const int k = tid;
        rec[k][0] = prm[k];        rec[k][1] = prm[k+1];
        rec[k][2] = prm[17+k];     rec[k][3] = prm[17+k+1];
        rec[k][4] = prm[34+k];     rec[k][5] = prm[34+k+1];
        rec[k][6] = 0.f;           rec[k][7] = 0.f;
        scan_s[k] = prm[k+1];      // thresholds cumw[1..16]
    }
    __syncthreads();

    float cw[KB];
    #pragma unroll
    for (int q = 0; q < 4; ++q) {
        const float4 t4 = *(const float4*)&scan_s[4*q];   // uniform broadcast
        cw[4*q+0] = t4.x; cw[4*q+1] = t4.y; cw[4*q+2] = t4.z; cw[4*q+3] = t4.w;
    }

    const size_t base = (size_t)b * NCOL + 4*tid;
    const float4 yv   = *(const float4*)(y + base);
    const float  yy[4] = {yv.x, yv.y, yv.z, yv.w};
    float ov[4], lv[4];

    #pragma unroll
    for (int i = 0; i < 4; ++i) {
        const float yi = yy[i];
        const bool outside = (yi < -BOUNDF) || (yi > BOUNDF);
        const float xc = fminf(fmaxf(yi, -BOUNDF), BOUNDF);
        int bin = 0;
        #pragma unroll
        for (int k = 0; k < KB; ++k) bin += (xc >= cw[k]) ? 1 : 0;
        bin = min(bin, KB-1);

        const float4 lo = *(const float4*)&rec[bin][0];   // ds_read_b128
        const float2 hi = *(const float2*)&rec[bin][4];   // ds_read_b64
        const float w  = lo.y - lo.x;
        const float hh = lo.w - lo.z;
        const float d0 = hi.x, d1 = hi.y;

        const float inv_w = __fdividef(1.f, w);
        const float delta = hh * inv_w;
        const float theta = (xc - lo.x) * inv_w;
        const float omt   = 1.f - theta;
        const float tt    = theta * theta;
        const float tomt  = theta * omt;
        const float num   = hh * (delta*tt + d0*tomt);
        const float den   = delta + (d0 + d1 - 2.f*delta)*tomt;
        const float o     = lo.z + __fdividef(num, den);
        const float der_num = fmaxf(delta*delta*(d1*tt + 2.f*delta*tomt + d0*omt*omt), 1e-12f);
        const float der_den = fmaxf(den*den, 1e-12f);
        const float ld      = __logf(__fdividef(der_num, der_den));

        ov[i] = outside ? yi : o;
        lv[i] = outside ? 0.f : ld;
    }

    *(float4*)(out + base)    = make_float4(ov[0], ov[1], ov[2], ov[3]);
    *(float4*)(logdet + base) = make_float4(lv[0], lv[1], lv[2], lv[3]);
}

extern "C" void kernel_launch(void* const* d_in, const int* in_sizes, int n_in,
                              void* d_out, int out_size, void* d_ws, size_t ws_size,
                              hipStream_t stream) {
    const float* cond = (const float*)d_in[0];
    const float* y    = (const float*)d_in[1];
    const float* W1   = (const float*)d_in[2];
    const float* b1   = (const float*)d_in[3];
    const float* W2   = (const float*)d_in[4];
    const float* b2   = (const float*)d_in[5];
    const float* W3   = (const float*)d_in[6];
    const float* b3   = (const float*)d_in[7];

    float* out    = (float*)d_out;
    float* logdet = out + (size_t)NROW * NCOL;
    float* params = (float*)d_ws;   // 4096 * 51 floats = 0.84 MB

    mlp_params_kernel<<<NROW/NR, NT, 0, stream>>>(cond, W1, b1, W2, b2, W3, b3, params);
    spline_kernel<<<NROW, 256, 0, stream>>>(y, params, out, logdet);
}